// Round 4
// baseline (1005.981 us; speedup 1.0000x reference)
//
#include <hip/hip_runtime.h>
#include <hip/hip_fp16.h>

#define IN_F 4096
#define OUT_F 4096
#define TOK 8192
#define NNZ_PER_ROW 205
#define NNZ (OUT_F * NNZ_PER_ROW)

typedef __attribute__((ext_vector_type(8))) _Float16 f16x8;
typedef __attribute__((ext_vector_type(4))) float floatx4;

// ---------------- fused prep: dequant+sparse (per W row) + cvt_x ----------
// Blocks [0, OUT_F): one block per W row. Dequant the row into an LDS row
// buffer, apply the row's CSR residual (cols sorted -> run-dedup, single
// writer per (row,col)), store the row once. Eliminates the sparse_add
// global RMW round-trip and two kernel launches.
// Blocks [OUT_F, OUT_F + TOK*IN_F/8/256): x fp32->fp16 conversion chunks.

__global__ __launch_bounds__(256) void prep_fused_kernel(const float* __restrict__ x,
                                                         _Float16* __restrict__ xh,
                                                         const int* __restrict__ bp,
                                                         const float* __restrict__ scales,
                                                         const void* __restrict__ vals_raw,
                                                         const int* __restrict__ cols,
                                                         _Float16* __restrict__ wh) {
    __shared__ _Float16 rowbuf[IN_F];            // 8 KB
    const int b = blockIdx.x;

    if (b < OUT_F) {
        const float s = scales[b];
        const int4* p = (const int4*)(bp + (size_t)b * IN_F);
#pragma unroll
        for (int it = 0; it < 2; ++it) {
            int t = it * 256 + threadIdx.x;      // 0..511, 8 ints each
            int4 a = p[t * 2], c = p[t * 2 + 1];
            f16x8 h;
            h[0] = (_Float16)((float)(a.x - 128) * s);
            h[1] = (_Float16)((float)(a.y - 128) * s);
            h[2] = (_Float16)((float)(a.z - 128) * s);
            h[3] = (_Float16)((float)(a.w - 128) * s);
            h[4] = (_Float16)((float)(c.x - 128) * s);
            h[5] = (_Float16)((float)(c.y - 128) * s);
            h[6] = (_Float16)((float)(c.z - 128) * s);
            h[7] = (_Float16)((float)(c.w - 128) * s);
            *(f16x8*)&rowbuf[t * 8] = h;
        }
        __syncthreads();

        // dtype sniff (fp16 bit-pairs read as fp32 are < ~1e-12)
        const float*    vf = (const float*)vals_raw;
        const _Float16* vh = (const _Float16*)vals_raw;
        float mx = 0.f;
        for (int i = 0; i < 64; ++i) {
            float a = __builtin_fabsf(vf[i]);
            mx = a > mx ? a : mx;
        }
        const bool is_f32 = (mx > 1e-6f) && (mx < 1.0f);

        const int kk = threadIdx.x;
        if (kk < NNZ_PER_ROW) {
            const int rbeg = b * NNZ_PER_ROW;
            const int rend = rbeg + NNZ_PER_ROW;
            const int k    = rbeg + kk;
            const int c    = cols[k];
            if (kk == 0 || cols[k - 1] != c) {   // first of its run
                float sum = is_f32 ? vf[k] : (float)vh[k];
                for (int k2 = k + 1; k2 < rend && cols[k2] == c; ++k2)
                    sum += is_f32 ? vf[k2] : (float)vh[k2];
                rowbuf[c] = (_Float16)((float)rowbuf[c] + sum);
            }
        }
        __syncthreads();

        f16x8* dst = (f16x8*)(wh + (size_t)b * IN_F);
#pragma unroll
        for (int it = 0; it < 2; ++it) {
            int t = it * 256 + threadIdx.x;
            dst[t] = *(f16x8*)&rowbuf[t * 8];
        }
    } else {
        int t = (b - OUT_F) * 256 + threadIdx.x; // one thread = 8 elements
        const float4* p = (const float4*)x + (size_t)t * 2;
        float4 a = p[0], c = p[1];
        f16x8 h;
        h[0] = (_Float16)a.x; h[1] = (_Float16)a.y; h[2] = (_Float16)a.z; h[3] = (_Float16)a.w;
        h[4] = (_Float16)c.x; h[5] = (_Float16)c.y; h[6] = (_Float16)c.z; h[7] = (_Float16)c.w;
        ((f16x8*)xh)[t] = h;
    }
}

// ---------------- standalone prep kernels (fallback path only) ------------

__global__ __launch_bounds__(256) void cvt_x_kernel(const float* __restrict__ x,
                                                    _Float16* __restrict__ xh) {
    int t = blockIdx.x * 256 + threadIdx.x;
    const float4* p = (const float4*)x + (size_t)t * 2;
    float4 a = p[0], b = p[1];
    f16x8 h;
    h[0] = (_Float16)a.x; h[1] = (_Float16)a.y; h[2] = (_Float16)a.z; h[3] = (_Float16)a.w;
    h[4] = (_Float16)b.x; h[5] = (_Float16)b.y; h[6] = (_Float16)b.z; h[7] = (_Float16)b.w;
    ((f16x8*)xh)[t] = h;
}

__global__ __launch_bounds__(256) void dequant_w_kernel(const int* __restrict__ bp,
                                                        const float* __restrict__ scales,
                                                        _Float16* __restrict__ wh) {
    int t = blockIdx.x * 256 + threadIdx.x;
    int row = t >> 9;
    float s = scales[row];
    const int4* p = (const int4*)bp + (size_t)t * 2;
    int4 a = p[0], b = p[1];
    f16x8 h;
    h[0] = (_Float16)((float)(a.x - 128) * s);
    h[1] = (_Float16)((float)(a.y - 128) * s);
    h[2] = (_Float16)((float)(a.z - 128) * s);
    h[3] = (_Float16)((float)(a.w - 128) * s);
    h[4] = (_Float16)((float)(b.x - 128) * s);
    h[5] = (_Float16)((float)(b.y - 128) * s);
    h[6] = (_Float16)((float)(b.z - 128) * s);
    h[7] = (_Float16)((float)(b.w - 128) * s);
    ((f16x8*)wh)[t] = h;
}

__global__ __launch_bounds__(256) void sparse_add_kernel(const void* __restrict__ vals_raw,
                                                         const int* __restrict__ cols,
                                                         _Float16* __restrict__ wh) {
    int k = blockIdx.x * 256 + threadIdx.x;
    if (k >= NNZ) return;

    const float*    vf = (const float*)vals_raw;
    const _Float16* vh = (const _Float16*)vals_raw;
    float mx = 0.f;
    for (int i = 0; i < 64; ++i) {
        float a = __builtin_fabsf(vf[i]);
        mx = a > mx ? a : mx;
    }
    const bool is_f32 = (mx > 1e-6f) && (mx < 1.0f);

    int row  = k / NNZ_PER_ROW;
    int rbeg = row * NNZ_PER_ROW;
    int rend = rbeg + NNZ_PER_ROW;
    int c    = cols[k];
    if (k != rbeg && cols[k - 1] == c) return;

    float s = is_f32 ? vf[k] : (float)vh[k];
    for (int k2 = k + 1; k2 < rend && cols[k2] == c; ++k2)
        s += is_f32 ? vf[k2] : (float)vh[k2];

    _Float16* p = wh + (size_t)row * IN_F + c;
    *p = (_Float16)((float)*p + s);
}

// ---------------- GEMM: 256x256 tile, frag-dbuf + strength-reduced addrs ---
// Structure identical to round 3 (fragment double-buffering, 4 barriers/kt,
// vmcnt(0) only at ph2 pre-barrier). This round: kt unrolled by 2 so buf is
// compile-time; 8 loop-invariant per-lane LDS base pointers make every
// ds_read_b128 a reg+imm access (zero per-iteration VALU); staging uses
// 4 precomputed per-lane invariant offsets + uniform kcol (1 v_add/load).

__global__ __launch_bounds__(512, 2) void gemm256_kernel(const _Float16* __restrict__ X,
                                                         const _Float16* __restrict__ W,
                                                         float* __restrict__ out) {
    extern __shared__ char smem[];               // 131072 bytes
    const int tid  = threadIdx.x;
    const int lane = tid & 63;
    const int w    = tid >> 6;                   // 0..7
    const int wm   = w >> 2;                     // 0..1  (M)
    const int wn   = w & 3;                      // 0..3  (N)

    // bijective XCD swizzle: 512 blocks, 64 contiguous logical tiles per XCD
    const int bid = blockIdx.x;
    const int swz = (bid & 7) * 64 + (bid >> 3);
    const int bm  = swz >> 4;                    // 0..31
    const int bn  = swz & 15;                    // 0..15

    const _Float16* Ap = X + (size_t)(bm * 256) * IN_F;
    const _Float16* Bp = W + (size_t)(bn * 256) * IN_F;

    // staging lane geometry: chunk = 8 rows x 128B = 1024B; within a chunk
    // lane>>3 = row, lane&7 = LDS slot; global chunk fetched = slot ^ row&7.
    const int l8 = lane >> 3;
    const int e  = (lane & 7) ^ l8;              // per-lane constant

    // loop-invariant per-lane staging offsets (elements): [rowBaseIdx][j]
    int sinv[2][2];
#pragma unroll
    for (int j = 0; j < 2; ++j) {
        sinv[0][j] = ((w * 2 + j) * 8 + l8) * IN_F + e * 8;
        sinv[1][j] = (128 + (w * 2 + j) * 8 + l8) * IN_F + e * 8;
    }

    auto stage = [&](const _Float16* panel, int ldsBase, int rbIdx, int kcol) {
#pragma unroll
        for (int j = 0; j < 2; ++j) {
            const _Float16* gp = panel + sinv[rbIdx][j] + kcol;   // 1 v_add
            char* lp = smem + ldsBase + (w * 2 + j) * 1024;       // wave-uniform
            __builtin_amdgcn_global_load_lds(
                (const __attribute__((address_space(1))) void*)gp,
                (__attribute__((address_space(3))) void*)lp, 16, 0, 0);
        }
    };

    const int q     = lane >> 4;
    const int r15   = lane & 15;
    const int slot0 = (q ^ (r15 & 7)) * 16;      // kk0 slot byte; kk1 = slot0^64

    // 8 loop-invariant per-lane LDS base pointers (A/B x kk0/kk1 x buf0/buf1)
    char* const aRow = smem + (wm * 128 + r15) * 128;
    char* const bRow = smem + 32768 + (wn * 64 + r15) * 128;
    const char* const A00 = aRow + slot0;                 // buf0 kk0
    const char* const A01 = aRow + (slot0 ^ 64);          // buf0 kk1
    const char* const A10 = aRow + 65536 + slot0;         // buf1 kk0
    const char* const A11 = aRow + 65536 + (slot0 ^ 64);  // buf1 kk1
    const char* const B00 = bRow + slot0;
    const char* const B01 = bRow + (slot0 ^ 64);
    const char* const B10 = bRow + 65536 + slot0;
    const char* const B11 = bRow + 65536 + (slot0 ^ 64);

    floatx4 acc[8][4] = {};
    f16x8 sa0[4], sa1[4], sb0[4], sb1[4];

#define DS_A(DST, P, MQ) do {                                                   \
    _Pragma("unroll")                                                           \
    for (int mt = 0; mt < 4; ++mt)                                              \
        DST[mt] = *(const f16x8*)((P) + (MQ) * 8192 + mt * 2048);               \
} while (0)

#define DS_B(DST, P) do {                                                       \
    _Pragma("unroll")                                                           \
    for (int nt = 0; nt < 4; ++nt)                                              \
        DST[nt] = *(const f16x8*)((P) + nt * 2048);                             \
} while (0)

#define MFMA4(SA, SB, MQ) do {                                                  \
    __builtin_amdgcn_s_setprio(1);                                              \
    _Pragma("unroll")                                                           \
    for (int mt = 0; mt < 4; ++mt)                                              \
        _Pragma("unroll")                                                       \
        for (int nt = 0; nt < 4; ++nt)                                          \
            acc[(MQ) * 4 + mt][nt] = __builtin_amdgcn_mfma_f32_16x16x32_f16(    \
                SA[mt], SB[nt], acc[(MQ) * 4 + mt][nt], 0, 0, 0);               \
    __builtin_amdgcn_s_setprio(0);                                              \
} while (0)

// One K-tile (4 phases). AC0/AC1/BC1 = cur-buf kk0/kk1 bases; AN0/BN0 =
// other-buf kk0 bases (next tile's ph0 set); OB/BUF = LDS byte bases.
#define TILE(KT, AC0, AC1, BC1, AN0, BN0, OB, BUF) do {                         \
    /* ph0: MFMA(mq0,kk0); prefetch A(mq1,kk0); stage A1(kt+1) */               \
    DS_A(sa1, AC0, 1);                                                          \
    if ((KT) < 63) stage(Ap, (OB), 0, ((KT) + 1) * 64);                         \
    __builtin_amdgcn_sched_barrier(0);                                          \
    MFMA4(sa0, sb0, 0);                                                         \
    __builtin_amdgcn_s_barrier();                                               \
    /* ph1: MFMA(mq1,kk0); prefetch A(mq0,kk1)+B(kk1); stage A2(kt+1) */        \
    DS_A(sa0, AC1, 0);                                                          \
    DS_B(sb1, BC1);                                                             \
    if ((KT) < 63) stage(Ap, (OB) + 16384, 1, ((KT) + 1) * 64);                 \
    __builtin_amdgcn_sched_barrier(0);                                          \
    MFMA4(sa1, sb0, 1);                                                         \
    __builtin_amdgcn_s_barrier();                                               \
    /* ph2: MFMA(mq0,kk1); prefetch A(mq1,kk1); vmcnt(0) pre-barrier */         \
    DS_A(sa1, AC1, 1);                                                          \
    __builtin_amdgcn_sched_barrier(0);                                          \
    MFMA4(sa0, sb1, 0);                                                         \
    asm volatile("s_waitcnt vmcnt(0)" ::: "memory");                            \
    __builtin_amdgcn_s_barrier();                                               \
    /* ph3: MFMA(mq1,kk1); prefetch next tile (mq0,kk0); stage B(kt+2) */       \
    if ((KT) < 63) { DS_A(sa0, AN0, 0); DS_B(sb0, BN0); }                       \
    if ((KT) < 62) {                                                            \
        stage(Bp, (BUF) + 32768, 0, ((KT) + 2) * 64);                           \
        stage(Bp, (BUF) + 49152, 1, ((KT) + 2) * 64);                           \
    }                                                                           \
    __builtin_amdgcn_sched_barrier(0);                                          \
    MFMA4(sa1, sb1, 1);                                                         \
    __builtin_amdgcn_s_barrier();                                               \
} while (0)

    // prologue: tile 0 fully + B(1); drain; preload ph0 fragment set
    stage(Bp, 32768, 0, 0);            // B1(0)
    stage(Bp, 49152, 1, 0);            // B2(0)
    stage(Ap, 0, 0, 0);                // A1(0)
    stage(Ap, 16384, 1, 0);            // A2(0)
    stage(Bp, 65536 + 32768, 0, 64);   // B1(1)
    stage(Bp, 65536 + 49152, 1, 64);   // B2(1)
    asm volatile("s_waitcnt vmcnt(0)" ::: "memory");
    __builtin_amdgcn_s_barrier();
    DS_A(sa0, A00, 0);
    DS_B(sb0, B00);

    for (int kt = 0; kt < 64; kt += 2) {
        TILE(kt,     A00, A01, B01, A10, B10, 65536, 0);
        TILE(kt + 1, A10, A11, B11, A00, B00, 0, 65536);
    }

#undef DS_A
#undef DS_B
#undef MFMA4
#undef TILE

#pragma unroll
    for (int mq = 0; mq < 2; ++mq)
#pragma unroll
        for (int mt = 0; mt < 4; ++mt)
#pragma unroll
            for (int nt = 0; nt < 4; ++nt) {
                const int o    = bn * 256 + wn * 64 + nt * 16 + r15;
                const int trow = bm * 256 + wm * 128 + mq * 64 + mt * 16 + q * 4;
                const floatx4 v = acc[mq * 4 + mt][nt];
#pragma unroll
                for (int r = 0; r < 4; ++r)
                    out[(size_t)(trow + r) * OUT_F + o] = v[r];
            }
}

// ---------------- GEMM fallbacks (previous known-good kernels) -------------

__global__ __launch_bounds__(256) void gemm_fast_kernel(const _Float16* __restrict__ X,
                                                        const _Float16* __restrict__ W,
                                                        float* __restrict__ out) {
    __shared__ __align__(1024) char smem[32768];   // A: [0,16K)  B: [16K,32K)
    const int tid  = threadIdx.x;
    const int lane = tid & 63;
    const int w    = tid >> 6;
    const int wm   = w >> 1;
    const int wn   = w & 1;
    const int bm   = blockIdx.y;
    const int bn   = blockIdx.x;

    const int l8 = lane >> 3;
    const int ls = lane & 7;
    const int e  = ls ^ l8;

    floatx4 acc[4][4] = {};

    for (int k0 = 0; k0 < IN_F; k0 += 64) {
#pragma unroll
        for (int j = 0; j < 4; ++j) {
            int c   = w * 4 + j;
            int row = c * 8 + l8;
            const _Float16* gp = X + ((size_t)(bm * 128 + row)) * IN_F + k0 + e * 8;
            char* lp = smem + c * 1024;
            __builtin_amdgcn_global_load_lds((const __attribute__((address_space(1))) void*)gp,
                                             (__attribute__((address_space(3))) void*)lp,
                                             16, 0, 0);
        }
#pragma unroll
        for (int j = 0; j < 4; ++j) {
            int c   = w * 4 + j;
            int row = c * 8 + l8;
            const _Float16* gp = W + ((size_t)(bn * 128 + row)) * IN_F + k0 + e * 8;
            char* lp = smem + 16384 + c * 1024;
            __builtin_amdgcn_global_load_lds((const __attribute__((address_space(1))) void*)gp,
                                             (__attribute__((address_space(3))) void*)lp,
                                             16, 0, 0);
        }
        __syncthreads();

        const int q   = lane >> 4;
        const int r15 = lane & 15;
#pragma unroll
        for (int kk = 0; kk < 64; kk += 32) {
            int j = (kk >> 3) + q;
            f16x8 a[4], b[4];
#pragma unroll
            for (int mt = 0; mt < 4; ++mt) {
                int row = wm * 64 + mt * 16 + r15;
                a[mt] = *(const f16x8*)(smem + row * 128 + ((j ^ (row & 7)) * 16));
            }
#pragma unroll
            for (int nt = 0; nt < 4; ++nt) {
                int row = wn * 64 + nt * 16 + r15;
                b[nt] = *(const f16x8*)(smem + 16384 + row * 128 + ((j ^ (row & 7)) * 16));
            }
#pragma unroll
            for (int mt = 0; mt < 4; ++mt)
#pragma unroll
                for (int nt = 0; nt < 4; ++nt)
                    acc[mt][nt] = __builtin_amdgcn_mfma_f32_16x16x32_f16(a[mt], b[nt],
                                                                         acc[mt][nt], 0, 0, 0);
        }
        __syncthreads();
    }

    const int q   = lane >> 4;
    const int r15 = lane & 15;
#pragma unroll
    for (int mt = 0; mt < 4; ++mt)
#pragma unroll
        for (int nt = 0; nt < 4; ++nt) {
            int o     = bn * 128 + wn * 64 + nt * 16 + r15;
            int tbase = bm * 128 + wm * 64 + mt * 16 + q * 4;
#pragma unroll
            for (int r = 0; r < 4; ++r)
                out[(size_t)(tbase + r) * OUT_F + o] = acc[mt][nt][r];
        }
}

__global__ __launch_bounds__(256) void gemm_kernel(const float* __restrict__ X,
                                                   const _Float16* __restrict__ W,
                                                   float* __restrict__ out) {
    __shared__ __align__(16) _Float16 As[128 * 72];
    __shared__ __align__(16) _Float16 Bs[128 * 72];
    const int tid  = threadIdx.x;
    const int lane = tid & 63;
    const int w    = tid >> 6;
    const int wm   = w >> 1;
    const int wn   = w & 1;
    const int bm   = blockIdx.y;
    const int bn   = blockIdx.x;
    const int srow = tid >> 3;
    const int sch  = tid & 7;

    const float*    Xb = X + (size_t)(bm * 128) * IN_F;
    const _Float16* Wb = W + (size_t)(bn * 128) * IN_F;

    floatx4 acc[4][4] = {};

    for (int k0 = 0; k0 < IN_F; k0 += 64) {
#pragma unroll
        for (int p = 0; p < 4; ++p) {
            int row = p * 32 + srow;
            const float* gp = Xb + (size_t)row * IN_F + k0 + sch * 8;
            float4 u = ((const float4*)gp)[0];
            float4 v = ((const float4*)gp)[1];
            f16x8 h;
            h[0] = (_Float16)u.x; h[1] = (_Float16)u.y;
            h[2] = (_Float16)u.z; h[3] = (_Float16)u.w;
            h[4] = (_Float16)v.x; h[5] = (_Float16)v.y;
            h[6] = (_Float16)v.z; h[7] = (_Float16)v.w;
            *(f16x8*)&As[row * 72 + sch * 8] = h;
        }
#pragma unroll
        for (int p = 0; p < 4; ++p) {
            int row = p * 32 + srow;
            *(f16x8*)&Bs[row * 72 + sch * 8] =
                *(const f16x8*)(Wb + (size_t)row * IN_F + k0 + sch * 8);
        }
        __syncthreads();

        const int q   = lane >> 4;
        const int r15 = lane & 15;
#pragma unroll
        for (int kk = 0; kk < 64; kk += 32) {
            int j = (kk >> 3) + q;
            f16x8 a[4], b[4];
#pragma unroll
            for (int mt = 0; mt < 4; ++mt) {
                int row = wm * 64 + mt * 16 + r15;
                a[mt] = *(const f16x8*)&As[row * 72 + j * 8];
            }
#pragma unroll
            for (int nt = 0; nt < 4; ++nt) {
                int row = wn * 64 + nt * 16 + r15;
                b[nt] = *(const f16x8*)&Bs[row * 72 + j * 8];
            }
#pragma unroll
            for (int mt = 0; mt < 4; ++mt)
#pragma unroll
                for (int nt = 0; nt < 4; ++nt)
                    acc[mt][nt] = __builtin_amdgcn_mfma_f32_16x16x32_f16(a[mt], b[nt],
                                                                         acc[mt][nt], 0, 0, 0);
        }
        __syncthreads();
    }

    const int q   = lane >> 4;
    const int r15 = lane & 15;
#pragma unroll
    for (int mt = 0; mt < 4; ++mt)
#pragma unroll
        for (int nt = 0; nt < 4; ++nt) {
            int o     = bn * 128 + wn * 64 + nt * 16 + r15;
            int tbase = bm * 128 + wm * 64 + mt * 16 + q * 4;
#pragma unroll
            for (int r = 0; r < 4; ++r)
                out[(size_t)(tbase + r) * OUT_F + o] = acc[mt][nt][r];
        }
}

// ---------------- launch ----------------

extern "C" void kernel_launch(void* const* d_in, const int* in_sizes, int n_in,
                              void* d_out, int out_size, void* d_ws, size_t ws_size,
                              hipStream_t stream) {
    const float* x      = (const float*)d_in[0];
    const int*   bp     = (const int*)d_in[1];
    const float* scales = (const float*)d_in[2];
    const void*  vals   = (const void*)d_in[3];
    const int*   cols   = (const int*)d_in[4];
    float*       out    = (float*)d_out;

    _Float16* wh = (_Float16*)d_ws;                                    // 33.5 MB
    const size_t wh_bytes = (size_t)OUT_F * IN_F * 2;
    const size_t xh_bytes = (size_t)TOK * IN_F * 2;                    // 67 MB

    static int use256 = -1;
    if (use256 < 0) {
        hipError_t err = hipFuncSetAttribute((const void*)gemm256_kernel,
                                             hipFuncAttributeMaxDynamicSharedMemorySize,
                                             131072);
        use256 = (err == hipSuccess) ? 1 : 0;
    }

    if (ws_size >= wh_bytes + xh_bytes) {
        _Float16* xh = (_Float16*)((char*)d_ws + wh_bytes);
        prep_fused_kernel<<<OUT_F + TOK * IN_F / 8 / 256, 256, 0, stream>>>(
            x, xh, bp, scales, vals, cols, wh);
        if (use256) {
            gemm256_kernel<<<dim3(512), 512, 131072, stream>>>(xh, wh, out);
        } else {
            dim3 grid(OUT_F / 128, TOK / 128);
            gemm_fast_kernel<<<grid, 256, 0, stream>>>(xh, wh, out);
        }
    } else {
        dequant_w_kernel<<<OUT_F * IN_F / 8 / 256, 256, 0, stream>>>(bp, scales, wh);
        sparse_add_kernel<<<(NNZ + 255) / 256, 256, 0, stream>>>(vals, cols, wh);
        dim3 grid(OUT_F / 128, TOK / 128);
        gemm_kernel<<<grid, 256, 0, stream>>>(x, wh, out);
    }
}